// Round 1
// baseline (461.019 us; speedup 1.0000x reference)
//
#include <hip/hip_runtime.h>
#include <cstddef>

typedef __attribute__((ext_vector_type(8))) short s16x8;
typedef __attribute__((ext_vector_type(4))) float f32x4;

static __device__ __forceinline__ float bf2f(unsigned short u) {
    union { unsigned u; float f; } v;
    v.u = ((unsigned)u) << 16;
    return v.f;
}

static __device__ __forceinline__ unsigned short f2bf(float f) {
    union { float f; unsigned u; } v;
    v.f = f;
    unsigned r = v.u + 0x7fffu + ((v.u >> 16) & 1u);  // RNE
    return (unsigned short)(r >> 16);
}

// dtype-generic scalar load -> float
static __device__ __forceinline__ float ldf(const unsigned short* p, size_t i) { return bf2f(p[i]); }
static __device__ __forceinline__ float ldf(const float* p, size_t i) { return p[i]; }
// dtype-generic store from float
static __device__ __forceinline__ void stf(unsigned short* p, size_t i, float v) { p[i] = f2bf(v); }
static __device__ __forceinline__ void stf(float* p, size_t i, float v) { p[i] = v; }

// ---------------------------------------------------------------------------
// dtype probe: read q as bf16; true-bf16 N(0,1) data -> max ~5.
// fp32 data read as ushort pairs -> garbage exponents (>>1e3) or NaN.
// flags[0]: 0 = inputs are bf16, 1 = inputs are fp32.
// flags[1]: zeroed here; probe_zero sets it to 1 if att_mask has any nonzero.
// ---------------------------------------------------------------------------
__global__ __launch_bounds__(256) void probe_dtype(
    const unsigned short* __restrict__ q, unsigned* __restrict__ flags)
{
    __shared__ float red[256];
    const int t = threadIdx.x;
    float m = 0.0f;
    for (int i = t; i < 16384; i += 256) {
        float x = fabsf(bf2f(q[i]));
        if (!(x == x)) x = 1.0e30f;  // NaN -> huge
        m = fmaxf(m, x);
    }
    red[t] = m;
    __syncthreads();
    for (int s = 128; s > 0; s >>= 1) {
        if (t < s) red[t] = fmaxf(red[t], red[t + s]);
        __syncthreads();
    }
    if (t == 0) {
        flags[0] = (red[0] < 1000.0f) ? 0u : 1u;
        flags[1] = 0u;
    }
}

// ---------------------------------------------------------------------------
// att_mask all-zero probe (bitwise: works for fp32 and bf16 alike).
// Sets flags[1]=1 iff any nonzero bits found. Runs after probe_dtype
// (stream-serialized), reads flags[0] for the element width.
// ---------------------------------------------------------------------------
__global__ __launch_bounds__(256) void probe_zero(
    const uint4* __restrict__ m, unsigned* __restrict__ flags)
{
    const unsigned dt = flags[0];
    // B*S*S = 8,388,608 elems; fp32 -> 2,097,152 uint4; bf16 -> 1,048,576
    const size_t n = dt ? 2097152u : 1048576u;
    unsigned acc = 0;
    for (size_t i = (size_t)blockIdx.x * 256 + threadIdx.x; i < n;
         i += (size_t)gridDim.x * 256) {
        uint4 v = m[i];
        acc |= v.x | v.y | v.z | v.w;
    }
    if (acc) atomicOr(&flags[1], 1u);
}

// ---------------------------------------------------------------------------
// Weight transpose to bf16: dst[n][k] = (bf16)src[k][n], 1024x1024
// ---------------------------------------------------------------------------
template <typename T>
__global__ __launch_bounds__(256) void transpose_w(
    const T* __restrict__ src, unsigned short* __restrict__ dst,
    const unsigned* __restrict__ flag, unsigned want)
{
    if (*flag != want) return;
    __shared__ unsigned short tile[32][33];
    const int c0 = blockIdx.x * 32, r0 = blockIdx.y * 32;
    const int tx = threadIdx.x, ty = threadIdx.y;  // block (32,8)
#pragma unroll
    for (int i = 0; i < 32; i += 8)
        tile[ty + i][tx] = f2bf(ldf(src, (size_t)(r0 + ty + i) * 1024 + c0 + tx));
    __syncthreads();
#pragma unroll
    for (int i = 0; i < 32; i += 8)
        dst[(size_t)(c0 + ty + i) * 1024 + r0 + tx] = tile[tx][ty + i];
}

// ---------------------------------------------------------------------------
// GEMM: C[M=4096,N=1024] = A[4096,1024] @ Bt[1024,1024]^T  (Bt is [N][K] bf16)
// 64x64 tile, 256 threads = 4 waves.
// mode 0: plain row-major store (TO dtype)
// mode 1: head-split store  out[((b*16+h)*2048 + s)*64 + d]   (bf16)
// mode 2: transposed head-split (V): out[((b*16+h)*64 + d)*2048 + s]  (bf16)
// ---------------------------------------------------------------------------
template <typename TA, typename TO>
__global__ __launch_bounds__(256) void gemm_kernel(
    const TA* __restrict__ A, const unsigned short* __restrict__ Bt,
    TO* __restrict__ out, int mode, const unsigned* __restrict__ flag, unsigned want)
{
    if (*flag != want) return;
    const int K = 1024;
    __shared__ __align__(16) unsigned short lA[64 * 72];
    __shared__ __align__(16) unsigned short lB[64 * 72];

    const int m0 = blockIdx.y * 64, n0 = blockIdx.x * 64;
    const int t = threadIdx.x;
    const int w = t >> 6, l = t & 63, quad = l >> 4, l15 = l & 15;
    const int srow = t >> 2, scol = (t & 3) * 16;

    f32x4 acc[4] = {};

    for (int k0 = 0; k0 < K; k0 += 64) {
        if constexpr (sizeof(TA) == 2) {
            const uint4* ga = (const uint4*)(A + (size_t)(m0 + srow) * K + k0 + scol);
            uint4 a0 = ga[0], a1 = ga[1];
            *(uint4*)&lA[srow * 72 + scol] = a0;
            *(uint4*)&lA[srow * 72 + scol + 8] = a1;
        } else {
            const TA* gaf = A + (size_t)(m0 + srow) * K + k0 + scol;
            unsigned short tmp[16];
#pragma unroll
            for (int j = 0; j < 16; j++) tmp[j] = f2bf((float)gaf[j]);
#pragma unroll
            for (int j = 0; j < 16; j++) lA[srow * 72 + scol + j] = tmp[j];
        }
        const uint4* gb = (const uint4*)(Bt + (size_t)(n0 + srow) * K + k0 + scol);
        uint4 b0 = gb[0], b1 = gb[1];
        *(uint4*)&lB[srow * 72 + scol] = b0;
        *(uint4*)&lB[srow * 72 + scol + 8] = b1;
        __syncthreads();
#pragma unroll
        for (int kk = 0; kk < 64; kk += 32) {
            s16x8 af = *(const s16x8*)&lA[(w * 16 + l15) * 72 + kk + quad * 8];
#pragma unroll
            for (int g = 0; g < 4; g++) {
                s16x8 bf = *(const s16x8*)&lB[(g * 16 + l15) * 72 + kk + quad * 8];
                acc[g] = __builtin_amdgcn_mfma_f32_16x16x32_bf16(af, bf, acc[g], 0, 0, 0);
            }
        }
        __syncthreads();
    }

#pragma unroll
    for (int g = 0; g < 4; g++) {
#pragma unroll
        for (int r = 0; r < 4; r++) {
            int row = m0 + w * 16 + quad * 4 + r;
            int col = n0 + g * 16 + l15;
            float val = acc[g][r];
            if (mode == 0) {
                stf(out, (size_t)row * 1024 + col, val);
            } else {
                int b = row >> 11, s = row & 2047;
                int h = col >> 6, d = col & 63;
                if (mode == 1)
                    stf(out, (((size_t)(b * 16 + h) * 2048) + s) * 64 + d, val);
                else
                    stf(out, (((size_t)(b * 16 + h) * 64) + d) * 2048 + s, val);
            }
        }
    }
}

// ---------------------------------------------------------------------------
// Flash attention with post-softmax multiplicative seq_mask.
// qh, kh: [B,H,S,64] bf16; vt: [B,H,64,S] bf16; masks: [B,S,S] dtype TM.
// l = sum exp(s-m) over ALL keys; O += (exp(s-m)*seq_mask)@V; final O/l.
// seq_mask is staged per-tile into LDS as bf16 via coalesced 16B loads
// (replaces 16 scalar global loads/thread/tile). att_mask is skipped
// entirely when the runtime zero-probe (flags[1]==0) proved it all-zero.
// ---------------------------------------------------------------------------
template <typename TM>
__global__ __launch_bounds__(256) void attn_kernel(
    const unsigned short* __restrict__ qh, const unsigned short* __restrict__ kh,
    const unsigned short* __restrict__ vt, const TM* __restrict__ amask,
    const TM* __restrict__ smask, unsigned short* __restrict__ aout,
    const unsigned* __restrict__ flags, unsigned want)
{
    if (flags[0] != want) return;
    const bool useA = (flags[1] != 0u);
    const int S = 2048, DK = 64, H = 16;
    const int qt = blockIdx.x, h = blockIdx.y, b = blockIdx.z;
    const unsigned short* qhb = qh + (size_t)(b * H + h) * S * DK;
    const unsigned short* khb = kh + (size_t)(b * H + h) * S * DK;
    const unsigned short* vtb = vt + (size_t)(b * H + h) * DK * S;
    const TM* amb = amask + (size_t)b * S * S;
    const TM* smb = smask + (size_t)b * S * S;

    __shared__ __align__(16) unsigned short lK[64 * 72];
    __shared__ __align__(16) unsigned short lV[64 * 72];
    __shared__ __align__(16) unsigned short lM[64 * 72];
    __shared__ __align__(16) unsigned short lP[4][16 * 72];

    const int t = threadIdx.x;
    const int w = t >> 6, l = t & 63, quad = l >> 4, l15 = l & 15;
    const int q0 = qt * 64;
    const int srow = t >> 2, scol = (t & 3) * 16;

    const int qrow_a = q0 + w * 16 + l15;
    s16x8 qf0 = *(const s16x8*)&qhb[(size_t)qrow_a * DK + quad * 8];
    s16x8 qf1 = *(const s16x8*)&qhb[(size_t)qrow_a * DK + 32 + quad * 8];

    float mrun[4], lrun[4];
    f32x4 o[4] = {};
#pragma unroll
    for (int r = 0; r < 4; r++) { mrun[r] = -INFINITY; lrun[r] = 0.0f; }

    for (int k0 = 0; k0 < S; k0 += 64) {
        const uint4* gk = (const uint4*)&khb[(size_t)(k0 + srow) * DK + scol];
        const uint4* gv = (const uint4*)&vtb[(size_t)srow * S + k0 + scol];
        uint4 ka = gk[0], kb = gk[1];
        uint4 va = gv[0], vb = gv[1];
        // stage seq_mask tile [64 q-rows][64 k-cols] -> bf16 LDS
        if constexpr (sizeof(TM) == 4) {
            const float4* gmf = (const float4*)(smb + (size_t)(q0 + srow) * S + k0 + scol);
            float4 a0 = gmf[0], a1 = gmf[1], a2 = gmf[2], a3 = gmf[3];
            uint4 u0, u1;
            u0.x = f2bf(a0.x) | ((unsigned)f2bf(a0.y) << 16);
            u0.y = f2bf(a0.z) | ((unsigned)f2bf(a0.w) << 16);
            u0.z = f2bf(a1.x) | ((unsigned)f2bf(a1.y) << 16);
            u0.w = f2bf(a1.z) | ((unsigned)f2bf(a1.w) << 16);
            u1.x = f2bf(a2.x) | ((unsigned)f2bf(a2.y) << 16);
            u1.y = f2bf(a2.z) | ((unsigned)f2bf(a2.w) << 16);
            u1.z = f2bf(a3.x) | ((unsigned)f2bf(a3.y) << 16);
            u1.w = f2bf(a3.z) | ((unsigned)f2bf(a3.w) << 16);
            *(uint4*)&lK[srow * 72 + scol] = ka;
            *(uint4*)&lK[srow * 72 + scol + 8] = kb;
            *(uint4*)&lV[srow * 72 + scol] = va;
            *(uint4*)&lV[srow * 72 + scol + 8] = vb;
            *(uint4*)&lM[srow * 72 + scol] = u0;
            *(uint4*)&lM[srow * 72 + scol + 8] = u1;
        } else {
            const uint4* gmu = (const uint4*)(smb + (size_t)(q0 + srow) * S + k0 + scol);
            uint4 m0 = gmu[0], m1 = gmu[1];
            *(uint4*)&lK[srow * 72 + scol] = ka;
            *(uint4*)&lK[srow * 72 + scol + 8] = kb;
            *(uint4*)&lV[srow * 72 + scol] = va;
            *(uint4*)&lV[srow * 72 + scol + 8] = vb;
            *(uint4*)&lM[srow * 72 + scol] = m0;
            *(uint4*)&lM[srow * 72 + scol + 8] = m1;
        }
        __syncthreads();

        f32x4 sc[4] = {};
#pragma unroll
        for (int kk = 0; kk < 64; kk += 32) {
            s16x8 af = (kk == 0) ? qf0 : qf1;
#pragma unroll
            for (int g = 0; g < 4; g++) {
                s16x8 bf = *(const s16x8*)&lK[(g * 16 + l15) * 72 + kk + quad * 8];
                sc[g] = __builtin_amdgcn_mfma_f32_16x16x32_bf16(af, bf, sc[g], 0, 0, 0);
            }
        }

#pragma unroll
        for (int r = 0; r < 4; r++) {
            const int qr = q0 + w * 16 + quad * 4 + r;
            const int lrow = w * 16 + quad * 4 + r;  // q-row within tile
            const size_t mrow = (size_t)qr * S + k0;
            float av[4];
            if (useA) {
#pragma unroll
                for (int g = 0; g < 4; g++) av[g] = ldf(amb, mrow + g * 16 + l15);
            } else {
#pragma unroll
                for (int g = 0; g < 4; g++) av[g] = 0.0f;
            }
            float sv[4];
            float mx = -INFINITY;
#pragma unroll
            for (int g = 0; g < 4; g++) {
                float s = sc[g][r] * 0.125f + av[g];
                sv[g] = s;
                mx = fmaxf(mx, s);
            }
#pragma unroll
            for (int d = 1; d < 16; d <<= 1) mx = fmaxf(mx, __shfl_xor(mx, d));
            float mnew = fmaxf(mrun[r], mx);
            float rs = 0.0f;
#pragma unroll
            for (int g = 0; g < 4; g++) {
                float e = __expf(sv[g] - mnew);
                sv[g] = e;
                rs += e;
            }
#pragma unroll
            for (int d = 1; d < 16; d <<= 1) rs += __shfl_xor(rs, d);
            float alpha = __expf(mrun[r] - mnew);
            lrun[r] = lrun[r] * alpha + rs;
            mrun[r] = mnew;
#pragma unroll
            for (int g = 0; g < 4; g++) o[g][r] *= alpha;
#pragma unroll
            for (int g = 0; g < 4; g++) {
                float pm = sv[g] * bf2f(lM[lrow * 72 + g * 16 + l15]);
                lP[w][(quad * 4 + r) * 72 + g * 16 + l15] = f2bf(pm);
            }
        }
        __syncthreads();

#pragma unroll
        for (int kk = 0; kk < 64; kk += 32) {
            s16x8 pf = *(const s16x8*)&lP[w][l15 * 72 + kk + quad * 8];
#pragma unroll
            for (int g = 0; g < 4; g++) {
                s16x8 vf = *(const s16x8*)&lV[(g * 16 + l15) * 72 + kk + quad * 8];
                o[g] = __builtin_amdgcn_mfma_f32_16x16x32_bf16(pf, vf, o[g], 0, 0, 0);
            }
        }
        __syncthreads();
    }

#pragma unroll
    for (int r = 0; r < 4; r++) {
        float inv = 1.0f / lrun[r];
        const int qr = q0 + w * 16 + quad * 4 + r;
#pragma unroll
        for (int g = 0; g < 4; g++) {
            aout[((size_t)(b * S + qr)) * 1024 + h * 64 + g * 16 + l15] =
                f2bf(o[g][r] * inv);
        }
    }
}

// ---------------------------------------------------------------------------
extern "C" void kernel_launch(void* const* d_in, const int* in_sizes, int n_in,
                              void* d_out, int out_size, void* d_ws, size_t ws_size,
                              hipStream_t stream)
{
    // setup_inputs order: q, v, k, att_mask, seq_mask, Wq, Wk, Wv, Wo
    const void* q   = d_in[0];
    const void* v   = d_in[1];
    const void* k   = d_in[2];
    const void* att = d_in[3];
    const void* seq = d_in[4];
    const void* Wq  = d_in[5];
    const void* Wk  = d_in[6];
    const void* Wv  = d_in[7];
    const void* Wo  = d_in[8];

    const size_t WELEM = 1024 * 1024;
    const size_t HELEM = (size_t)2 * 16 * 2048 * 64;  // 4,194,304 elements

    unsigned* flags = (unsigned*)d_ws;
    unsigned short* base = (unsigned short*)((char*)d_ws + 512);
    unsigned short* r0 = base;           // phase A: Wq^T,Wk^T,Wv^T ; phase B: ao
    unsigned short* qh = base + HELEM;   // phase A: qh ; phase C: Wo^T
    unsigned short* kh = qh + HELEM;
    unsigned short* vt = kh + HELEM;
    // total ws: 512 + 4*HELEM*2 = 33.6 MB

    const dim3 tg(32, 32), tb(32, 8);
    const dim3 gg(16, 64), gb(256);
    const dim3 ag(32, 16, 2), ab(256);

    probe_dtype<<<1, 256, 0, stream>>>((const unsigned short*)q, flags);
    probe_zero<<<1024, 256, 0, stream>>>((const uint4*)att, flags);

    // ---- transposes of Wq, Wk, Wv (both dtype variants; one no-ops) ----
    transpose_w<unsigned short><<<tg, tb, 0, stream>>>((const unsigned short*)Wq, r0 + 0 * WELEM, flags, 0);
    transpose_w<unsigned short><<<tg, tb, 0, stream>>>((const unsigned short*)Wk, r0 + 1 * WELEM, flags, 0);
    transpose_w<unsigned short><<<tg, tb, 0, stream>>>((const unsigned short*)Wv, r0 + 2 * WELEM, flags, 0);
    transpose_w<float><<<tg, tb, 0, stream>>>((const float*)Wq, r0 + 0 * WELEM, flags, 1);
    transpose_w<float><<<tg, tb, 0, stream>>>((const float*)Wk, r0 + 1 * WELEM, flags, 1);
    transpose_w<float><<<tg, tb, 0, stream>>>((const float*)Wv, r0 + 2 * WELEM, flags, 1);

    // ---- projections ----
    gemm_kernel<unsigned short, unsigned short><<<gg, gb, 0, stream>>>((const unsigned short*)q, r0 + 0 * WELEM, qh, 1, flags, 0);
    gemm_kernel<unsigned short, unsigned short><<<gg, gb, 0, stream>>>((const unsigned short*)k, r0 + 1 * WELEM, kh, 1, flags, 0);
    gemm_kernel<unsigned short, unsigned short><<<gg, gb, 0, stream>>>((const unsigned short*)v, r0 + 2 * WELEM, vt, 2, flags, 0);
    gemm_kernel<float, unsigned short><<<gg, gb, 0, stream>>>((const float*)q, r0 + 0 * WELEM, qh, 1, flags, 1);
    gemm_kernel<float, unsigned short><<<gg, gb, 0, stream>>>((const float*)k, r0 + 1 * WELEM, kh, 1, flags, 1);
    gemm_kernel<float, unsigned short><<<gg, gb, 0, stream>>>((const float*)v, r0 + 2 * WELEM, vt, 2, flags, 1);

    // ---- attention (ao overwrites r0; weights no longer needed) ----
    unsigned short* ao = r0;
    attn_kernel<unsigned short><<<ag, ab, 0, stream>>>(qh, kh, vt, (const unsigned short*)att, (const unsigned short*)seq, ao, flags, 0);
    attn_kernel<float><<<ag, ab, 0, stream>>>(qh, kh, vt, (const float*)att, (const float*)seq, ao, flags, 1);

    // ---- Wo transpose into qh region (qh no longer needed) ----
    transpose_w<unsigned short><<<tg, tb, 0, stream>>>((const unsigned short*)Wo, qh, flags, 0);
    transpose_w<float><<<tg, tb, 0, stream>>>((const float*)Wo, qh, flags, 1);

    // ---- output projection ----
    gemm_kernel<unsigned short, unsigned short><<<gg, gb, 0, stream>>>(ao, qh, (unsigned short*)d_out, 0, flags, 0);
    gemm_kernel<unsigned short, float><<<gg, gb, 0, stream>>>(ao, qh, (float*)d_out, 0, flags, 1);
}

// Round 2
// 435.928 us; speedup vs baseline: 1.0576x; 1.0576x over previous
//
#include <hip/hip_runtime.h>
#include <cstddef>

typedef __attribute__((ext_vector_type(8))) short s16x8;
typedef __attribute__((ext_vector_type(4))) float f32x4;
typedef __attribute__((ext_vector_type(4))) unsigned short us4;

static __device__ __forceinline__ float bf2f(unsigned short u) {
    union { unsigned u; float f; } v;
    v.u = ((unsigned)u) << 16;
    return v.f;
}

static __device__ __forceinline__ unsigned short f2bf(float f) {
    union { float f; unsigned u; } v;
    v.f = f;
    unsigned r = v.u + 0x7fffu + ((v.u >> 16) & 1u);  // RNE
    return (unsigned short)(r >> 16);
}

// dtype-generic scalar load -> float
static __device__ __forceinline__ float ldf(const unsigned short* p, size_t i) { return bf2f(p[i]); }
static __device__ __forceinline__ float ldf(const float* p, size_t i) { return p[i]; }
// dtype-generic store from float
static __device__ __forceinline__ void stf(unsigned short* p, size_t i, float v) { p[i] = f2bf(v); }
static __device__ __forceinline__ void stf(float* p, size_t i, float v) { p[i] = v; }

// ---------------------------------------------------------------------------
// dtype probe: read q as bf16; true-bf16 N(0,1) data -> max ~5.
// fp32 data read as ushort pairs -> garbage exponents (>>1e3) or NaN.
// flags[0]: 0 = inputs are bf16, 1 = inputs are fp32.
// flags[1]: zeroed here; probe_zero sets it to 1 if att_mask has any nonzero.
// ---------------------------------------------------------------------------
__global__ __launch_bounds__(256) void probe_dtype(
    const unsigned short* __restrict__ q, unsigned* __restrict__ flags)
{
    __shared__ float red[256];
    const int t = threadIdx.x;
    float m = 0.0f;
    for (int i = t; i < 16384; i += 256) {
        float x = fabsf(bf2f(q[i]));
        if (!(x == x)) x = 1.0e30f;  // NaN -> huge
        m = fmaxf(m, x);
    }
    red[t] = m;
    __syncthreads();
    for (int s = 128; s > 0; s >>= 1) {
        if (t < s) red[t] = fmaxf(red[t], red[t + s]);
        __syncthreads();
    }
    if (t == 0) {
        flags[0] = (red[0] < 1000.0f) ? 0u : 1u;
        flags[1] = 0u;
    }
}

// ---------------------------------------------------------------------------
// att_mask all-zero probe (bitwise: works for fp32 and bf16 alike).
// Sets flags[1]=1 iff any nonzero bits found.
// ---------------------------------------------------------------------------
__global__ __launch_bounds__(256) void probe_zero(
    const uint4* __restrict__ m, unsigned* __restrict__ flags)
{
    const unsigned dt = flags[0];
    // B*S*S = 8,388,608 elems; fp32 -> 2,097,152 uint4; bf16 -> 1,048,576
    const size_t n = dt ? 2097152u : 1048576u;
    unsigned acc = 0;
    for (size_t i = (size_t)blockIdx.x * 256 + threadIdx.x; i < n;
         i += (size_t)gridDim.x * 256) {
        uint4 v = m[i];
        acc |= v.x | v.y | v.z | v.w;
    }
    if (acc) atomicOr(&flags[1], 1u);
}

// ---------------------------------------------------------------------------
// fp32 -> bf16 bulk convert (runs iff flags[0]==1). gate: skip unless
// flags[1]!=0 when gate!=0 (unused this round; kept for generality).
// ---------------------------------------------------------------------------
__global__ __launch_bounds__(256) void cvt_f32_bf16(
    const float4* __restrict__ src, us4* __restrict__ dst, unsigned n4,
    const unsigned* __restrict__ flags, unsigned gate)
{
    if (flags[0] != 1u) return;
    if (gate != 0u && flags[1] == 0u) return;
    for (unsigned i = blockIdx.x * 256u + threadIdx.x; i < n4;
         i += gridDim.x * 256u) {
        float4 v = src[i];
        us4 o;
        o.x = f2bf(v.x); o.y = f2bf(v.y); o.z = f2bf(v.z); o.w = f2bf(v.w);
        dst[i] = o;
    }
}

// bf16 passthrough copy (runs iff flags[0]==0)
__global__ __launch_bounds__(256) void copy_bf16(
    const uint4* __restrict__ src, uint4* __restrict__ dst, unsigned n16,
    const unsigned* __restrict__ flags, unsigned gate)
{
    if (flags[0] != 0u) return;
    if (gate != 0u && flags[1] == 0u) return;
    for (unsigned i = blockIdx.x * 256u + threadIdx.x; i < n16;
         i += gridDim.x * 256u)
        dst[i] = src[i];
}

// ---------------------------------------------------------------------------
// Weight transpose to bf16: dst[n][k] = (bf16)src[k][n], 1024x1024
// ---------------------------------------------------------------------------
template <typename T>
__global__ __launch_bounds__(256) void transpose_w(
    const T* __restrict__ src, unsigned short* __restrict__ dst,
    const unsigned* __restrict__ flag, unsigned want)
{
    if (*flag != want) return;
    __shared__ unsigned short tile[32][33];
    const int c0 = blockIdx.x * 32, r0 = blockIdx.y * 32;
    const int tx = threadIdx.x, ty = threadIdx.y;  // block (32,8)
#pragma unroll
    for (int i = 0; i < 32; i += 8)
        tile[ty + i][tx] = f2bf(ldf(src, (size_t)(r0 + ty + i) * 1024 + c0 + tx));
    __syncthreads();
#pragma unroll
    for (int i = 0; i < 32; i += 8)
        dst[(size_t)(c0 + ty + i) * 1024 + r0 + tx] = tile[tx][ty + i];
}

// ---------------------------------------------------------------------------
// GEMM: C[M=4096,N=1024] = A[4096,1024] @ Bt[1024,1024]^T
// A is ALWAYS bf16 now (inputs pre-converted). 64x64 tile, 4 waves.
// want==2 -> always run; else gated on flags[0]==want (for output dtype).
// mode 0: plain row-major store (TO dtype)
// mode 1: head-split store  out[((b*16+h)*2048 + s)*64 + d]   (bf16)
// mode 2: transposed head-split (V): out[((b*16+h)*64 + d)*2048 + s]  (bf16)
// ---------------------------------------------------------------------------
template <typename TO>
__global__ __launch_bounds__(256) void gemm_kernel(
    const unsigned short* __restrict__ A, const unsigned short* __restrict__ Bt,
    TO* __restrict__ out, int mode, const unsigned* __restrict__ flags, unsigned want)
{
    if (want != 2u && flags[0] != want) return;
    const int K = 1024;
    __shared__ __align__(16) unsigned short lA[64 * 72];
    __shared__ __align__(16) unsigned short lB[64 * 72];

    const int m0 = blockIdx.y * 64, n0 = blockIdx.x * 64;
    const int t = threadIdx.x;
    const int w = t >> 6, l = t & 63, quad = l >> 4, l15 = l & 15;
    const int srow = t >> 2, scol = (t & 3) * 16;

    f32x4 acc[4] = {};

    for (int k0 = 0; k0 < K; k0 += 64) {
        const uint4* ga = (const uint4*)(A + (size_t)(m0 + srow) * K + k0 + scol);
        uint4 a0 = ga[0], a1 = ga[1];
        const uint4* gb = (const uint4*)(Bt + (size_t)(n0 + srow) * K + k0 + scol);
        uint4 b0 = gb[0], b1 = gb[1];
        *(uint4*)&lA[srow * 72 + scol] = a0;
        *(uint4*)&lA[srow * 72 + scol + 8] = a1;
        *(uint4*)&lB[srow * 72 + scol] = b0;
        *(uint4*)&lB[srow * 72 + scol + 8] = b1;
        __syncthreads();
#pragma unroll
        for (int kk = 0; kk < 64; kk += 32) {
            s16x8 af = *(const s16x8*)&lA[(w * 16 + l15) * 72 + kk + quad * 8];
#pragma unroll
            for (int g = 0; g < 4; g++) {
                s16x8 bf = *(const s16x8*)&lB[(g * 16 + l15) * 72 + kk + quad * 8];
                acc[g] = __builtin_amdgcn_mfma_f32_16x16x32_bf16(af, bf, acc[g], 0, 0, 0);
            }
        }
        __syncthreads();
    }

#pragma unroll
    for (int g = 0; g < 4; g++) {
#pragma unroll
        for (int r = 0; r < 4; r++) {
            int row = m0 + w * 16 + quad * 4 + r;
            int col = n0 + g * 16 + l15;
            float val = acc[g][r];
            if (mode == 0) {
                stf(out, (size_t)row * 1024 + col, val);
            } else {
                int b = row >> 11, s = row & 2047;
                int h = col >> 6, d = col & 63;
                if (mode == 1)
                    stf(out, (((size_t)(b * 16 + h) * 2048) + s) * 64 + d, val);
                else
                    stf(out, (((size_t)(b * 16 + h) * 64) + d) * 2048 + s, val);
            }
        }
    }
}

// ---------------------------------------------------------------------------
// Flash attention with post-softmax multiplicative seq_mask.
// qh, kh: [B,H,S,64] bf16; vt: [B,H,64,S] bf16; seq_mask: bf16 (preconverted);
// att_mask: original dtype TM, only read when the zero-probe found nonzeros.
// l = sum exp(s-m) over ALL keys; O += (exp(s-m)*seq_mask)@V; final O/l.
// ---------------------------------------------------------------------------
template <typename TM>
__global__ __launch_bounds__(256) void attn_kernel(
    const unsigned short* __restrict__ qh, const unsigned short* __restrict__ kh,
    const unsigned short* __restrict__ vt, const TM* __restrict__ amask,
    const unsigned short* __restrict__ smask, unsigned short* __restrict__ aout,
    const unsigned* __restrict__ flags, unsigned want)
{
    if (flags[0] != want) return;
    const bool useA = (flags[1] != 0u);
    const int S = 2048, DK = 64, H = 16;
    const int qt = blockIdx.x, h = blockIdx.y, b = blockIdx.z;
    const unsigned short* qhb = qh + (size_t)(b * H + h) * S * DK;
    const unsigned short* khb = kh + (size_t)(b * H + h) * S * DK;
    const unsigned short* vtb = vt + (size_t)(b * H + h) * DK * S;
    const TM* amb = amask + (size_t)b * S * S;
    const unsigned short* smb = smask + (size_t)b * S * S;

    __shared__ __align__(16) unsigned short lK[64 * 72];
    __shared__ __align__(16) unsigned short lV[64 * 72];
    __shared__ __align__(16) unsigned short lP[4][16 * 72];

    const int t = threadIdx.x;
    const int w = t >> 6, l = t & 63, quad = l >> 4, l15 = l & 15;
    const int q0 = qt * 64;
    const int srow = t >> 2, scol = (t & 3) * 16;

    const int qrow_a = q0 + w * 16 + l15;
    s16x8 qf0 = *(const s16x8*)&qhb[(size_t)qrow_a * DK + quad * 8];
    s16x8 qf1 = *(const s16x8*)&qhb[(size_t)qrow_a * DK + 32 + quad * 8];

    float mrun[4], lrun[4];
    f32x4 o[4] = {};
#pragma unroll
    for (int r = 0; r < 4; r++) { mrun[r] = -INFINITY; lrun[r] = 0.0f; }

    for (int k0 = 0; k0 < S; k0 += 64) {
        const uint4* gk = (const uint4*)&khb[(size_t)(k0 + srow) * DK + scol];
        const uint4* gv = (const uint4*)&vtb[(size_t)srow * S + k0 + scol];
        uint4 ka = gk[0], kb = gk[1];
        uint4 va = gv[0], vb = gv[1];
        *(uint4*)&lK[srow * 72 + scol] = ka;
        *(uint4*)&lK[srow * 72 + scol + 8] = kb;
        *(uint4*)&lV[srow * 72 + scol] = va;
        *(uint4*)&lV[srow * 72 + scol + 8] = vb;
        __syncthreads();

        f32x4 sc[4] = {};
#pragma unroll
        for (int kk = 0; kk < 64; kk += 32) {
            s16x8 af = (kk == 0) ? qf0 : qf1;
#pragma unroll
            for (int g = 0; g < 4; g++) {
                s16x8 bf = *(const s16x8*)&lK[(g * 16 + l15) * 72 + kk + quad * 8];
                sc[g] = __builtin_amdgcn_mfma_f32_16x16x32_bf16(af, bf, sc[g], 0, 0, 0);
            }
        }

#pragma unroll
        for (int r = 0; r < 4; r++) {
            const int qr = q0 + w * 16 + quad * 4 + r;
            const size_t mrow = (size_t)qr * S + k0;
            float sv[4];
            float mx = -INFINITY;
            if (useA) {
#pragma unroll
                for (int g = 0; g < 4; g++) {
                    float s = sc[g][r] * 0.125f + ldf(amb, mrow + g * 16 + l15);
                    sv[g] = s;
                    mx = fmaxf(mx, s);
                }
            } else {
#pragma unroll
                for (int g = 0; g < 4; g++) {
                    float s = sc[g][r] * 0.125f;
                    sv[g] = s;
                    mx = fmaxf(mx, s);
                }
            }
#pragma unroll
            for (int d = 1; d < 16; d <<= 1) mx = fmaxf(mx, __shfl_xor(mx, d));
            float mnew = fmaxf(mrun[r], mx);
            float rs = 0.0f;
#pragma unroll
            for (int g = 0; g < 4; g++) {
                float e = __expf(sv[g] - mnew);
                sv[g] = e;
                rs += e;
            }
#pragma unroll
            for (int d = 1; d < 16; d <<= 1) rs += __shfl_xor(rs, d);
            float alpha = __expf(mrun[r] - mnew);
            lrun[r] = lrun[r] * alpha + rs;
            mrun[r] = mnew;
#pragma unroll
            for (int g = 0; g < 4; g++) o[g][r] *= alpha;
#pragma unroll
            for (int g = 0; g < 4; g++) {
                float pm = sv[g] * bf2f(smb[mrow + g * 16 + l15]);
                lP[w][(quad * 4 + r) * 72 + g * 16 + l15] = f2bf(pm);
            }
        }
        __syncthreads();

#pragma unroll
        for (int kk = 0; kk < 64; kk += 32) {
            s16x8 pf = *(const s16x8*)&lP[w][l15 * 72 + kk + quad * 8];
#pragma unroll
            for (int g = 0; g < 4; g++) {
                s16x8 vf = *(const s16x8*)&lV[(g * 16 + l15) * 72 + kk + quad * 8];
                o[g] = __builtin_amdgcn_mfma_f32_16x16x32_bf16(pf, vf, o[g], 0, 0, 0);
            }
        }
        __syncthreads();
    }

#pragma unroll
    for (int r = 0; r < 4; r++) {
        float inv = 1.0f / lrun[r];
        const int qr = q0 + w * 16 + quad * 4 + r;
#pragma unroll
        for (int g = 0; g < 4; g++) {
            aout[((size_t)(b * S + qr)) * 1024 + h * 64 + g * 16 + l15] =
                f2bf(o[g][r] * inv);
        }
    }
}

// ---------------------------------------------------------------------------
extern "C" void kernel_launch(void* const* d_in, const int* in_sizes, int n_in,
                              void* d_out, int out_size, void* d_ws, size_t ws_size,
                              hipStream_t stream)
{
    // setup_inputs order: q, v, k, att_mask, seq_mask, Wq, Wk, Wv, Wo
    const void* q   = d_in[0];
    const void* v   = d_in[1];
    const void* k   = d_in[2];
    const void* att = d_in[3];
    const void* seq = d_in[4];
    const void* Wq  = d_in[5];
    const void* Wk  = d_in[6];
    const void* Wv  = d_in[7];
    const void* Wo  = d_in[8];

    const size_t WELEM = 1024 * 1024;
    const size_t HELEM = (size_t)2 * 16 * 2048 * 64;  // 4,194,304 elements

    unsigned* flags = (unsigned*)d_ws;
    unsigned short* base = (unsigned short*)((char*)d_ws + 512);
    unsigned short* r0 = base;           // 8MB: Wq^T,Wk^T,Wv^T ; later ao
    unsigned short* qh = base + HELEM;   // 8MB: qh ; later Wo^T
    unsigned short* kh = qh + HELEM;     // 8MB
    unsigned short* vt = kh + HELEM;     // 8MB
    unsigned short* qb = vt + HELEM;     // 8MB bf16(q)
    unsigned short* kb = qb + HELEM;     // 8MB bf16(k)
    unsigned short* vb = kb + HELEM;     // 8MB bf16(v)
    unsigned short* seqb = qb;           // 16MB bf16(seq_mask), overlaps qb+kb
                                         //  (written AFTER projections finish)
    // total ws: 512 + 7*8MB = 56.5 MB

    const dim3 tg(32, 32), tb(32, 8);
    const dim3 gg(16, 64), gb(256);
    const dim3 ag(32, 16, 2), ab(256);

    probe_dtype<<<1, 256, 0, stream>>>((const unsigned short*)q, flags);
    probe_zero<<<1024, 256, 0, stream>>>((const uint4*)att, flags);

    // ---- bulk convert q,k,v to bf16 (one of each pair no-ops on dtype) ----
    const unsigned n4h = 1048576u, n16h = 524288u;   // HELEM/4, HELEM/8
    cvt_f32_bf16<<<1024, 256, 0, stream>>>((const float4*)q, (us4*)qb, n4h, flags, 0);
    cvt_f32_bf16<<<1024, 256, 0, stream>>>((const float4*)k, (us4*)kb, n4h, flags, 0);
    cvt_f32_bf16<<<1024, 256, 0, stream>>>((const float4*)v, (us4*)vb, n4h, flags, 0);
    copy_bf16<<<1024, 256, 0, stream>>>((const uint4*)q, (uint4*)qb, n16h, flags, 0);
    copy_bf16<<<1024, 256, 0, stream>>>((const uint4*)k, (uint4*)kb, n16h, flags, 0);
    copy_bf16<<<1024, 256, 0, stream>>>((const uint4*)v, (uint4*)vb, n16h, flags, 0);

    // ---- transposes of Wq, Wk, Wv (both dtype variants; one no-ops) ----
    transpose_w<unsigned short><<<tg, tb, 0, stream>>>((const unsigned short*)Wq, r0 + 0 * WELEM, flags, 0);
    transpose_w<unsigned short><<<tg, tb, 0, stream>>>((const unsigned short*)Wk, r0 + 1 * WELEM, flags, 0);
    transpose_w<unsigned short><<<tg, tb, 0, stream>>>((const unsigned short*)Wv, r0 + 2 * WELEM, flags, 0);
    transpose_w<float><<<tg, tb, 0, stream>>>((const float*)Wq, r0 + 0 * WELEM, flags, 1);
    transpose_w<float><<<tg, tb, 0, stream>>>((const float*)Wk, r0 + 1 * WELEM, flags, 1);
    transpose_w<float><<<tg, tb, 0, stream>>>((const float*)Wv, r0 + 2 * WELEM, flags, 1);

    // ---- projections (always run; A is bf16) ----
    gemm_kernel<unsigned short><<<gg, gb, 0, stream>>>(qb, r0 + 0 * WELEM, qh, 1, flags, 2);
    gemm_kernel<unsigned short><<<gg, gb, 0, stream>>>(kb, r0 + 1 * WELEM, kh, 1, flags, 2);
    gemm_kernel<unsigned short><<<gg, gb, 0, stream>>>(vb, r0 + 2 * WELEM, vt, 2, flags, 2);

    // ---- seq_mask -> bf16 (overlaps qb/kb; projections already consumed them)
    const unsigned n4s = 2097152u, n16s = 1048576u;  // 8,388,608 elems
    cvt_f32_bf16<<<2048, 256, 0, stream>>>((const float4*)seq, (us4*)seqb, n4s, flags, 0);
    copy_bf16<<<2048, 256, 0, stream>>>((const uint4*)seq, (uint4*)seqb, n16s, flags, 0);

    // ---- attention (ao overwrites r0; weights no longer needed) ----
    unsigned short* ao = r0;
    attn_kernel<unsigned short><<<ag, ab, 0, stream>>>(qh, kh, vt, (const unsigned short*)att, seqb, ao, flags, 0);
    attn_kernel<float><<<ag, ab, 0, stream>>>(qh, kh, vt, (const float*)att, seqb, ao, flags, 1);

    // ---- Wo transpose into qh region (qh no longer needed) ----
    transpose_w<unsigned short><<<tg, tb, 0, stream>>>((const unsigned short*)Wo, qh, flags, 0);
    transpose_w<float><<<tg, tb, 0, stream>>>((const float*)Wo, qh, flags, 1);

    // ---- output projection ----
    gemm_kernel<unsigned short><<<gg, gb, 0, stream>>>(ao, qh, (unsigned short*)d_out, 0, flags, 0);
    gemm_kernel<float><<<gg, gb, 0, stream>>>(ao, qh, (float*)d_out, 0, flags, 1);
}